// Round 2
// baseline (3115.589 us; speedup 1.0000x reference)
//
#include <hip/hip_runtime.h>
#include <hip/hip_bf16.h>

typedef unsigned int u32;
typedef unsigned short u16;
typedef float f32x4 __attribute__((ext_vector_type(4)));
typedef __bf16 bf16x8 __attribute__((ext_vector_type(8)));

#define DEV __device__ __forceinline__

DEV float bf2f(u16 u) { return __uint_as_float(((u32)u) << 16); }
DEV u16 f2bf(float f) {
    u32 x = __float_as_uint(f);
    return (u16)((x + 0x7fffu + ((x >> 16) & 1u)) >> 16);
}
DEV void unpack2(u32 u, float& lo, float& hi) {
    lo = __uint_as_float(u << 16);
    hi = __uint_as_float(u & 0xffff0000u);
}

// ================= transpose+convert (K,N) f32 -> (N,K) bf16 =================
__global__ __launch_bounds__(256) void k_transpose(const float* __restrict__ in,
                                                   u16* __restrict__ out,
                                                   int K, int N) {
    __shared__ float tile[32][33];
    int bx = blockIdx.x * 32;  // along N
    int by = blockIdx.y * 32;  // along K
    #pragma unroll
    for (int i = threadIdx.y; i < 32; i += 8)
        tile[i][threadIdx.x] = in[(size_t)(by + i) * N + bx + threadIdx.x];
    __syncthreads();
    #pragma unroll
    for (int i = threadIdx.y; i < 32; i += 8)
        out[(size_t)(bx + i) * K + by + threadIdx.x] = f2bf(tile[threadIdx.x][i]);
}

// ================= concat qkv bias (f32) =================
__global__ void k_concat_bias(const float* __restrict__ qb, const float* __restrict__ kvb,
                              float* __restrict__ out) {
    int i = blockIdx.x * 256 + threadIdx.x;
    if (i < 1536) out[i] = (i < 512) ? qb[i] : kvb[i - 512];
}

// ================= position-bias MLP (all f32) =================
DEV void ln32_relu(float* y, const float* w, const float* b) {
    float m = 0.f;
    #pragma unroll
    for (int j = 0; j < 32; ++j) m += y[j];
    m *= (1.f / 32.f);
    float v = 0.f;
    #pragma unroll
    for (int j = 0; j < 32; ++j) { float d = y[j] - m; v += d * d; }
    float rstd = rsqrtf(v * (1.f / 32.f) + 1e-5f);
    #pragma unroll
    for (int j = 0; j < 32; ++j) {
        float t = (y[j] - m) * rstd * w[j] + b[j];
        y[j] = t > 0.f ? t : 0.f;
    }
}

template <int NC>
DEV void mmNC(const float* in, const float* W, const float* Bb, float* out) {
    #pragma unroll
    for (int j = 0; j < NC; ++j) {
        float a = Bb[j];
        #pragma unroll
        for (int k = 0; k < 32; ++k) a += in[k] * W[k * NC + j];
        out[j] = a;
    }
}

__global__ __launch_bounds__(256) void k_bias_mlp(
    const float* pp_w, const float* pp_b,
    const float* p1lw, const float* p1lb, const float* p1w, const float* p1b,
    const float* p2lw, const float* p2lb, const float* p2w, const float* p2b,
    const float* p3lw, const float* p3lb, const float* p3w, const float* p3b,
    float* __restrict__ bias_out) {
    __shared__ float pos[169 * 16];
    int t = threadIdx.x;
    if (t < 169) {
        float y[32], z[32], w16[16];
        float g0 = (float)(t / 13) - 6.f;
        float g1 = (float)(t % 13) - 6.f;
        #pragma unroll
        for (int j = 0; j < 32; ++j)
            y[j] = g0 * pp_w[j] + g1 * pp_w[32 + j] + pp_b[j];
        ln32_relu(y, p1lw, p1lb);
        mmNC<32>(y, p1w, p1b, z);
        ln32_relu(z, p2lw, p2lb);
        mmNC<32>(z, p2w, p2b, y);
        ln32_relu(y, p3lw, p3lb);
        mmNC<16>(y, p3w, p3b, w16);
        #pragma unroll
        for (int hh = 0; hh < 16; ++hh) pos[t * 16 + hh] = w16[hh];
    }
    __syncthreads();
    for (int e = t; e < 38416; e += 256) {
        int hh = e / 2401;
        int rem = e - hh * 2401;
        int n = rem / 49;
        int m = rem - n * 49;
        int idx = (n / 7 - m / 7 + 6) * 13 + (n % 7 - m % 7 + 6);
        bias_out[e] = pos[idx * 16 + hh];
    }
}

// ================= row LayerNorm (512 wide f32 in, bf16 out), 1 wave/row =================
DEV float wave_sum(float s) {
    #pragma unroll
    for (int off = 32; off > 0; off >>= 1) s += __shfl_xor(s, off, 64);
    return s;
}

__global__ __launch_bounds__(256) void k_ln_rows(const float* __restrict__ x,
                                                 const float* __restrict__ w,
                                                 const float* __restrict__ b,
                                                 u16* __restrict__ out, int nrows) {
    int wid = threadIdx.x >> 6, lane = threadIdx.x & 63;
    int row = blockIdx.x * 4 + wid;
    if (row >= nrows) return;
    const float4* xr = (const float4*)(x + (size_t)row * 512);
    float4 a0 = xr[2 * lane], a1 = xr[2 * lane + 1];
    float f[8] = {a0.x, a0.y, a0.z, a0.w, a1.x, a1.y, a1.z, a1.w};
    float s = 0.f;
    #pragma unroll
    for (int i = 0; i < 8; ++i) s += f[i];
    float mean = wave_sum(s) * (1.f / 512.f);
    float q = 0.f;
    #pragma unroll
    for (int i = 0; i < 8; ++i) { float d = f[i] - mean; q += d * d; }
    float rstd = rsqrtf(wave_sum(q) * (1.f / 512.f) + 1e-5f);
    const float4* wr = (const float4*)w;
    const float4* br = (const float4*)b;
    float4 w0 = wr[2 * lane], w1 = wr[2 * lane + 1];
    float4 b0 = br[2 * lane], b1 = br[2 * lane + 1];
    float wf[8] = {w0.x, w0.y, w0.z, w0.w, w1.x, w1.y, w1.z, w1.w};
    float bf_[8] = {b0.x, b0.y, b0.z, b0.w, b1.x, b1.y, b1.z, b1.w};
    u32 ow[4];
    #pragma unroll
    for (int i = 0; i < 4; ++i) {
        u16 lo = f2bf((f[2*i]   - mean) * rstd * wf[2*i]   + bf_[2*i]);
        u16 hi = f2bf((f[2*i+1] - mean) * rstd * wf[2*i+1] + bf_[2*i+1]);
        ow[i] = (u32)lo | ((u32)hi << 16);
    }
    ((uint4*)(out + (size_t)row * 512))[lane] = make_uint4(ow[0], ow[1], ow[2], ow[3]);
}

// ================= GEMM: C[M,N] = A[M,K]bf16 @ BT[N,ldb]bf16^T + bias =================
// EPI 0: bf16 store            EPI 1: f32 store + res(f32, stride N)
// EPI 2: bf16 store, exact GELU EPI 3: f32 read-modify-write add
template <int EPI>
__global__ __launch_bounds__(256) void k_gemm(const u16* __restrict__ A,
                                              const u16* __restrict__ BT, int ldb,
                                              const float* __restrict__ bias,
                                              const float* __restrict__ res,
                                              void* __restrict__ Cv,
                                              int M, int N, int K) {
    __shared__ __align__(16) u16 As[128 * 32];
    __shared__ __align__(16) u16 Bs[128 * 32];
    const int tid = threadIdx.x;
    const int rb = blockIdx.x * 128, cb = blockIdx.y * 128;
    const int w = tid >> 6, lane = tid & 63;
    const int wr = w >> 1, wc = w & 1;

    f32x4 acc[4][4];
    #pragma unroll
    for (int i = 0; i < 4; ++i)
        #pragma unroll
        for (int j = 0; j < 4; ++j) acc[i][j] = (f32x4){0.f, 0.f, 0.f, 0.f};

    const int srow = tid >> 1, scol = (tid & 1) * 16;
    const u16* ag = A + (size_t)(rb + srow) * K + scol;
    const u16* bg = BT + (size_t)(cb + srow) * ldb + scol;
    uint4* asl = (uint4*)&As[srow * 32 + scol];
    uint4* bsl = (uint4*)&Bs[srow * 32 + scol];

    for (int k0 = 0; k0 < K; k0 += 32) {
        uint4 a0 = *(const uint4*)(ag);
        uint4 a1 = *(const uint4*)(ag + 8);
        uint4 b0 = *(const uint4*)(bg);
        uint4 b1 = *(const uint4*)(bg + 8);
        ag += 32; bg += 32;
        __syncthreads();   // previous iteration's reads complete
        asl[0] = a0; asl[1] = a1;
        bsl[0] = b0; bsl[1] = b1;
        __syncthreads();   // tiles visible
        bf16x8 af[4], bfr[4];
        #pragma unroll
        for (int i = 0; i < 4; ++i) {
            af[i]  = *(const bf16x8*)&As[(wr * 64 + i * 16 + (lane & 15)) * 32 + (lane >> 4) * 8];
            bfr[i] = *(const bf16x8*)&Bs[(wc * 64 + i * 16 + (lane & 15)) * 32 + (lane >> 4) * 8];
        }
        #pragma unroll
        for (int i = 0; i < 4; ++i)
            #pragma unroll
            for (int j = 0; j < 4; ++j)
                acc[i][j] = __builtin_amdgcn_mfma_f32_16x16x32_bf16(af[i], bfr[j], acc[i][j], 0, 0, 0);
    }

    #pragma unroll
    for (int i = 0; i < 4; ++i) {
        #pragma unroll
        for (int j = 0; j < 4; ++j) {
            int col = cb + wc * 64 + j * 16 + (lane & 15);
            float bv = bias ? bias[col] : 0.f;
            #pragma unroll
            for (int r = 0; r < 4; ++r) {
                int row = rb + wr * 64 + i * 16 + (lane >> 4) * 4 + r;
                size_t idx = (size_t)row * N + col;
                float v = acc[i][j][r] + bv;
                if (EPI == 0) {
                    ((u16*)Cv)[idx] = f2bf(v);
                } else if (EPI == 1) {
                    ((float*)Cv)[idx] = v + res[idx];
                } else if (EPI == 2) {
                    v = 0.5f * v * (1.f + erff(v * 0.70710678118654752f));
                    ((u16*)Cv)[idx] = f2bf(v);
                } else {  // EPI == 3
                    float* C = (float*)Cv;
                    C[idx] = C[idx] + v;
                }
            }
        }
    }
}

// ================= attention: 1 wave per (window, head) =================
__global__ __launch_bounds__(256) void k_attn(const u16* __restrict__ qkv,
                                              const float* __restrict__ bias,
                                              u16* __restrict__ outp) {
    __shared__ __align__(16) u16 kv_lds[4][2][49 * 32];
    const int b = blockIdx.x;
    const int w = threadIdx.x >> 6, lane = threadIdx.x & 63;
    const int h = blockIdx.y * 4 + w;
    const size_t tokbase = (size_t)b * 49;

    const u16* kbase = qkv + tokbase * 1536 + 512 + h * 32;
    const u16* vbase = qkv + tokbase * 1536 + 1024 + h * 32;
    for (int c = lane; c < 196; c += 64) {
        int r = c >> 2, seg = c & 3;
        ((uint4*)&kv_lds[w][0][r * 32])[seg] = *(const uint4*)(kbase + (size_t)r * 1536 + seg * 8);
        ((uint4*)&kv_lds[w][1][r * 32])[seg] = *(const uint4*)(vbase + (size_t)r * 1536 + seg * 8);
    }

    const int n = lane;
    const bool act = n < 49;
    const int qn = act ? n : 0;
    float qv[32];
    {
        const u16* qrow = qkv + (tokbase + qn) * 1536 + h * 32;
        #pragma unroll
        for (int i = 0; i < 4; ++i) {
            uint4 v = ((const uint4*)qrow)[i];
            unpack2(v.x, qv[8*i+0], qv[8*i+1]);
            unpack2(v.y, qv[8*i+2], qv[8*i+3]);
            unpack2(v.z, qv[8*i+4], qv[8*i+5]);
            unpack2(v.w, qv[8*i+6], qv[8*i+7]);
        }
    }
    __syncthreads();

    const float* brow = bias + ((size_t)h * 49 + qn) * 49;
    const u32* ku = (const u32*)&kv_lds[w][0][0];
    float s[49];
    #pragma unroll
    for (int m = 0; m < 49; ++m) {
        float a = 0.f;
        #pragma unroll
        for (int dp = 0; dp < 16; ++dp) {
            float lo, hi;
            unpack2(ku[m * 16 + dp], lo, hi);
            a += qv[2*dp] * lo + qv[2*dp+1] * hi;
        }
        s[m] = a * 0.17677669529663689f + brow[m];
    }

    float mx = s[0];
    #pragma unroll
    for (int m = 1; m < 49; ++m) mx = fmaxf(mx, s[m]);
    float sum = 0.f;
    #pragma unroll
    for (int m = 0; m < 49; ++m) { s[m] = __expf(s[m] - mx); sum += s[m]; }
    float inv = 1.f / sum;

    float o[32];
    #pragma unroll
    for (int i = 0; i < 32; ++i) o[i] = 0.f;
    const u32* vu = (const u32*)&kv_lds[w][1][0];
    #pragma unroll
    for (int m = 0; m < 49; ++m) {
        float pm = s[m] * inv;
        #pragma unroll
        for (int dp = 0; dp < 16; ++dp) {
            float lo, hi;
            unpack2(vu[m * 16 + dp], lo, hi);
            o[2*dp]   += pm * lo;
            o[2*dp+1] += pm * hi;
        }
    }

    if (act) {
        u32 ow[16];
        #pragma unroll
        for (int i = 0; i < 16; ++i)
            ow[i] = (u32)f2bf(o[2*i]) | ((u32)f2bf(o[2*i+1]) << 16);
        uint4* orow = (uint4*)(outp + (tokbase + n) * 512 + h * 32);
        #pragma unroll
        for (int i = 0; i < 4; ++i)
            orow[i] = make_uint4(ow[4*i], ow[4*i+1], ow[4*i+2], ow[4*i+3]);
    }
}

// ================= launch =================
extern "C" void kernel_launch(void* const* d_in, const int* in_sizes, int n_in,
                              void* d_out, int out_size, void* d_ws, size_t ws_size,
                              hipStream_t stream) {
    const float* x      = (const float*)d_in[0];
    const float* ln1w   = (const float*)d_in[1];
    const float* ln1b   = (const float*)d_in[2];
    const float* q_w    = (const float*)d_in[3];
    const float* q_b    = (const float*)d_in[4];
    const float* kv_w   = (const float*)d_in[5];
    const float* kv_b   = (const float*)d_in[6];
    const float* proj_w = (const float*)d_in[7];
    const float* proj_b = (const float*)d_in[8];
    const float* pp_w   = (const float*)d_in[9];
    const float* pp_b   = (const float*)d_in[10];
    const float* p1lw   = (const float*)d_in[11];
    const float* p1lb   = (const float*)d_in[12];
    const float* p1w    = (const float*)d_in[13];
    const float* p1b    = (const float*)d_in[14];
    const float* p2lw   = (const float*)d_in[15];
    const float* p2lb   = (const float*)d_in[16];
    const float* p2w    = (const float*)d_in[17];
    const float* p2b    = (const float*)d_in[18];
    const float* p3lw   = (const float*)d_in[19];
    const float* p3lb   = (const float*)d_in[20];
    const float* p3w    = (const float*)d_in[21];
    const float* p3b    = (const float*)d_in[22];
    const float* ln2w   = (const float*)d_in[23];
    const float* ln2b   = (const float*)d_in[24];
    const float* fc1w   = (const float*)d_in[25];
    const float* fc1b   = (const float*)d_in[26];
    const float* fc2w   = (const float*)d_in[27];
    const float* fc2b   = (const float*)d_in[28];

    const size_t TOK = 100352;  // 2048 * 49
    char* ws = (char*)d_ws;
    float* out32 = (float*)d_out;  // also holds x2 (f32) between proj and fc2

    size_t off = 0;
    auto take = [&](size_t bytes) {
        size_t o = off;
        off += (bytes + 255) & ~(size_t)255;
        return o;
    };
    u16*   WTqkv  = (u16*)(ws + take(1536 * 512 * 2));
    u16*   WTproj = (u16*)(ws + take(512 * 512 * 2));
    u16*   WTfc1  = (u16*)(ws + take(2048 * 512 * 2));
    u16*   WTfc2  = (u16*)(ws + take(512 * 2048 * 2));
    float* qkvb   = (float*)(ws + take(1536 * 4));
    float* bias32 = (float*)(ws + take(38416 * 4));
    u16*   xn     = (u16*)(ws + take(TOK * 512 * 2));   // LN1 out; reused: attn_o, then x2n
    size_t fixed_end = off;

    dim3 t256(256);
    // weight transpose+convert (B^T bf16 layout for GEMM)
    k_transpose<<<dim3(16, 16), dim3(32, 8), 0, stream>>>(q_w, WTqkv, 512, 512);
    k_transpose<<<dim3(32, 16), dim3(32, 8), 0, stream>>>(kv_w, WTqkv + 512 * 512, 512, 1024);
    k_transpose<<<dim3(16, 16), dim3(32, 8), 0, stream>>>(proj_w, WTproj, 512, 512);
    k_transpose<<<dim3(64, 16), dim3(32, 8), 0, stream>>>(fc1w, WTfc1, 512, 2048);
    k_transpose<<<dim3(16, 64), dim3(32, 8), 0, stream>>>(fc2w, WTfc2, 2048, 512);
    k_concat_bias<<<6, t256, 0, stream>>>(q_b, kv_b, qkvb);
    k_bias_mlp<<<1, t256, 0, stream>>>(pp_w, pp_b, p1lw, p1lb, p1w, p1b,
                                       p2lw, p2lb, p2w, p2b, p3lw, p3lb, p3w, p3b, bias32);

    // LN1: x(f32) -> xn(bf16)
    k_ln_rows<<<TOK / 4, t256, 0, stream>>>(x, ln1w, ln1b, xn, (int)TOK);

    const size_t big_need = fixed_end + (size_t)TOK * 2048 * 2;
    if (big_need <= ws_size) {
        // -------- big layout: qkv (308MB) and h (411MB) share one region --------
        u16* qkv = (u16*)(ws + fixed_end);
        u16* h   = qkv;
        u16* attn_o = xn;  // xn dead after qkv GEMM

        k_gemm<0><<<dim3(784, 12), t256, 0, stream>>>(xn, WTqkv, 512, qkvb, nullptr,
                                                      qkv, (int)TOK, 1536, 512);
        k_attn<<<dim3(2048, 4), t256, 0, stream>>>(qkv, bias32, attn_o);
        // x2(f32, in d_out) = x + attn_o @ proj + b
        k_gemm<1><<<dim3(784, 4), t256, 0, stream>>>(attn_o, WTproj, 512, proj_b, x,
                                                     out32, (int)TOK, 512, 512);
        // LN2: d_out(f32) -> x2n(bf16, xn region)
        k_ln_rows<<<TOK / 4, t256, 0, stream>>>(out32, ln2w, ln2b, xn, (int)TOK);
        // h = gelu(x2n @ fc1 + b)
        k_gemm<2><<<dim3(784, 16), t256, 0, stream>>>(xn, WTfc1, 512, fc1b, nullptr,
                                                      h, (int)TOK, 2048, 512);
        // d_out += h @ fc2 + b
        k_gemm<3><<<dim3(784, 4), t256, 0, stream>>>(h, WTfc2, 2048, fc2b, nullptr,
                                                     out32, (int)TOK, 512, 2048);
    } else {
        // -------- small layout: chunk qkv over M (4x), fc over N (4x) --------
        off = fixed_end;
        u16* attn_o  = (u16*)(ws + take(TOK * 512 * 2));
        u16* scratch = (u16*)(ws + take(TOK * 512 * 2));  // qkv chunks (77MB) / h chunks (103MB)
        const size_t MC = TOK / 4;  // 25088 rows = 512 windows

        for (int mc = 0; mc < 4; ++mc) {
            const u16* xnc = xn + (size_t)mc * MC * 512;
            k_gemm<0><<<dim3(196, 12), t256, 0, stream>>>(xnc, WTqkv, 512, qkvb, nullptr,
                                                          scratch, (int)MC, 1536, 512);
            k_attn<<<dim3(512, 4), t256, 0, stream>>>(scratch, bias32,
                                                      attn_o + (size_t)mc * MC * 512);
        }
        k_gemm<1><<<dim3(784, 4), t256, 0, stream>>>(attn_o, WTproj, 512, proj_b, x,
                                                     out32, (int)TOK, 512, 512);
        k_ln_rows<<<TOK / 4, t256, 0, stream>>>(out32, ln2w, ln2b, xn, (int)TOK);
        for (int c = 0; c < 4; ++c) {
            k_gemm<2><<<dim3(784, 4), t256, 0, stream>>>(xn, WTfc1 + (size_t)c * 512 * 512, 512,
                                                         fc1b + c * 512, nullptr,
                                                         scratch, (int)TOK, 512, 512);
            k_gemm<3><<<dim3(784, 4), t256, 0, stream>>>(scratch, WTfc2 + c * 512, 2048,
                                                         (c == 0) ? fc2b : nullptr, nullptr,
                                                         out32, (int)TOK, 512, 512);
        }
    }
}